// Round 1
// baseline (1094.989 us; speedup 1.0000x reference)
//
#include <hip/hip_runtime.h>
#include <math.h>

#define EOS_IDX 2
#define BONUS_WEIGHT 0.1f

// One block per batch row. Online logsumexp over V elements (float4 loads),
// wave shuffle reduce + cross-wave LDS reduce, then per-row eos prob -> ws[b].
__global__ __launch_bounds__(1024) void eos_row_kernel(
    const float* __restrict__ logits,
    const int* __restrict__ lens,
    float* __restrict__ partial,
    int T, int V)
{
    const int b = blockIdx.x;
    const int len = lens[b];
    int pos = len - 1;
    if (pos < 0) pos = 0;
    if (pos > T - 1) pos = T - 1;
    const bool valid = (len > 1) && ((len - 1) < T);

    const float* row = logits + ((size_t)b * T + pos) * (size_t)V;
    const float4* row4 = (const float4*)row;
    const int n4 = V >> 2;  // V=32000 -> 8000, V % 4 == 0 per problem

    float eos_logit = 0.f;
    if (threadIdx.x == 0) eos_logit = row[EOS_IDX];

    // per-thread online logsumexp state
    float m = -INFINITY;
    float s = 0.f;
    for (int i = threadIdx.x; i < n4; i += blockDim.x) {
        float4 x = row4[i];
        float lm = fmaxf(fmaxf(x.x, x.y), fmaxf(x.z, x.w));
        float ls = expf(x.x - lm) + expf(x.y - lm) +
                   expf(x.z - lm) + expf(x.w - lm);
        if (lm > m) {
            s = s * expf(m - lm) + ls;
            m = lm;
        } else {
            s = s + ls * expf(lm - m);
        }
    }

    // wave (64-lane) butterfly reduce of (m, s)
    #pragma unroll
    for (int off = 32; off > 0; off >>= 1) {
        float om = __shfl_xor(m, off, 64);
        float os = __shfl_xor(s, off, 64);
        float nm = fmaxf(m, om);
        // m,om are finite here (every thread saw >= 7 elements)
        s = s * expf(m - nm) + os * expf(om - nm);
        m = nm;
    }

    // cross-wave reduce via LDS (blockDim=1024 -> 16 waves)
    __shared__ float sm[16];
    __shared__ float ss[16];
    const int wave = threadIdx.x >> 6;
    const int lane = threadIdx.x & 63;
    if (lane == 0) { sm[wave] = m; ss[wave] = s; }
    __syncthreads();

    if (wave == 0) {
        const int nw = blockDim.x >> 6;
        float m2 = (lane < nw) ? sm[lane] : -INFINITY;
        float s2 = (lane < nw) ? ss[lane] : 0.f;
        #pragma unroll
        for (int off = 32; off > 0; off >>= 1) {
            float om = __shfl_xor(m2, off, 64);
            float os = __shfl_xor(s2, off, 64);
            float nm = fmaxf(m2, om);
            float ea = (m2 == -INFINITY && nm == -INFINITY) ? 0.f : expf(m2 - nm);
            float eb = (om == -INFINITY && nm == -INFINITY) ? 0.f : expf(om - nm);
            s2 = s2 * ea + os * eb;
            m2 = nm;
        }
        if (lane == 0) {
            // lse = m2 + log(s2); prob = exp(eos - lse)
            float prob = expf(eos_logit - m2 - logf(s2));
            partial[b] = valid ? prob : 0.f;
        }
    }
}

// Single wave: sum B partials, scale, write scalar output.
__global__ __launch_bounds__(64) void eos_final_kernel(
    const float* __restrict__ partial, float* __restrict__ out, int B)
{
    float s = 0.f;
    for (int i = threadIdx.x; i < B; i += 64) s += partial[i];
    #pragma unroll
    for (int off = 32; off > 0; off >>= 1) s += __shfl_xor(s, off, 64);
    if (threadIdx.x == 0) out[0] = -(BONUS_WEIGHT * s) / (float)B;
}

extern "C" void kernel_launch(void* const* d_in, const int* in_sizes, int n_in,
                              void* d_out, int out_size, void* d_ws, size_t ws_size,
                              hipStream_t stream) {
    const float* logits = (const float*)d_in[0];
    // d_in[1] = targets (unused by the reference computation)
    const int* lens = (const int*)d_in[2];

    const int B = in_sizes[2];                 // 64
    const int T = in_sizes[1] / B;             // 128
    const int V = (int)((size_t)in_sizes[0] / ((size_t)B * T));  // 32000

    float* partial = (float*)d_ws;

    eos_row_kernel<<<B, 1024, 0, stream>>>(logits, lens, partial, T, V);
    eos_final_kernel<<<1, 64, 0, stream>>>(partial, (float*)d_out, B);
}